// Round 1
// baseline (922.324 us; speedup 1.0000x reference)
//
#include <hip/hip_runtime.h>

typedef __attribute__((ext_vector_type(4))) float f32x4;
typedef __attribute__((ext_vector_type(8))) short s16x8;
typedef __attribute__((ext_vector_type(4))) unsigned int u32x4;

static __device__ __forceinline__ unsigned short f2bf(float f) {
  unsigned int u = __builtin_bit_cast(unsigned int, f);
  u += 0x7fffu + ((u >> 16) & 1u);
  return (unsigned short)(u >> 16);
}
static __device__ __forceinline__ float sigm(float x) { return 1.0f / (1.0f + __expf(-x)); }

// ---------------- rmsnorm rows of length 1024: fp32 -> bf16 ----------------
__global__ __launch_bounds__(256) void rmsnorm_k(const float* __restrict__ x,
                                                 const float* __restrict__ w,
                                                 unsigned short* __restrict__ y) {
  const int row = blockIdx.x;
  const int tid = threadIdx.x;
  const float4* xp = (const float4*)(x + (long)row * 1024);
  float4 v = xp[tid];
  float ss = v.x * v.x + v.y * v.y + v.z * v.z + v.w * v.w;
  #pragma unroll
  for (int off = 32; off; off >>= 1) ss += __shfl_xor(ss, off, 64);
  __shared__ float sb[4];
  if ((tid & 63) == 0) sb[tid >> 6] = ss;
  __syncthreads();
  float tot = sb[0] + sb[1] + sb[2] + sb[3];
  float rs = rsqrtf(tot * (1.0f / 1024.0f) + 1e-6f);
  const float4* wp = (const float4*)w;
  float4 wv = wp[tid];
  ushort4 o;
  o.x = f2bf(v.x * rs * wv.x);
  o.y = f2bf(v.y * rs * wv.y);
  o.z = f2bf(v.z * rs * wv.z);
  o.w = f2bf(v.w * rs * wv.w);
  ((ushort4*)y)[(long)row * 256 + tid] = o;
}

// ---------------- fp32 -> bf16 convert (8 elems/thread) ----------------
__global__ __launch_bounds__(256) void cvt_bf16_k(const float* __restrict__ in,
                                                  unsigned short* __restrict__ out,
                                                  long n8) {
  long i = (long)blockIdx.x * 256 + threadIdx.x;
  if (i >= n8) return;
  const float4* p = (const float4*)in;
  float4 a = p[i * 2], b = p[i * 2 + 1];
  ushort4 lo, hi;
  lo.x = f2bf(a.x); lo.y = f2bf(a.y); lo.z = f2bf(a.z); lo.w = f2bf(a.w);
  hi.x = f2bf(b.x); hi.y = f2bf(b.y); hi.z = f2bf(b.z); hi.w = f2bf(b.w);
  ushort4* o = (ushort4*)out;
  o[i * 2] = lo;
  o[i * 2 + 1] = hi;
}

// ---------------- GEMM: C[M][N] = alpha * A[M][K] @ W[N][K]^T (+bias[n]) ----------------
// A, W bf16 (raw ushort bits). CT = unsigned short (bf16 out) or float.
// TRANS: store C transposed as C[n*TM + m] (bf16 only). Batched via blockIdx.z strides.
template <int BM, int BN, int WR, int WC, typename CT, bool TRANS>
__global__ __launch_bounds__(WR * WC * 64) void gemm_bt(
    const unsigned short* __restrict__ A, const unsigned short* __restrict__ W,
    CT* __restrict__ C, int M, int N, int K, long sA, long sW, long sC,
    const float* __restrict__ bias, float alpha, int TM) {
  constexpr int BK = 64;
  constexpr int LSTR = BK + 8;  // pad to kill 16-way bank conflicts
  constexpr int NT = WR * WC * 64;
  constexpr int WSM = BM / WR, WSN = BN / WC;
  constexpr int MR = WSM / 16, NR = WSN / 16;
  static_assert(BM * 8 % NT == 0 && BN * 8 % NT == 0, "staging divisibility");
  __shared__ unsigned short As[BM * LSTR];
  __shared__ unsigned short Ws[BN * LSTR];
  const int tid = threadIdx.x, lane = tid & 63, wid = tid >> 6;
  const int wr = wid / WC, wc = wid % WC;
  const int tileN = blockIdx.x * BN, tileM = blockIdx.y * BM;
  A += (long)blockIdx.z * sA;
  W += (long)blockIdx.z * sW;
  C += (long)blockIdx.z * sC;
  f32x4 acc[MR][NR];
  #pragma unroll
  for (int i = 0; i < MR; i++)
    #pragma unroll
    for (int j = 0; j < NR; j++) acc[i][j] = (f32x4){0.f, 0.f, 0.f, 0.f};
  const int fr = lane & 15, fq = lane >> 4;

  for (int k0 = 0; k0 < K; k0 += BK) {
    #pragma unroll
    for (int i = 0; i < (BM * 8) / NT; i++) {
      int c = tid + i * NT, r = c >> 3, c8 = (c & 7) * 8;
      *(u32x4*)(&As[r * LSTR + c8]) = *(const u32x4*)(A + (long)(tileM + r) * K + k0 + c8);
    }
    #pragma unroll
    for (int i = 0; i < (BN * 8) / NT; i++) {
      int c = tid + i * NT, r = c >> 3, c8 = (c & 7) * 8;
      *(u32x4*)(&Ws[r * LSTR + c8]) = *(const u32x4*)(W + (long)(tileN + r) * K + k0 + c8);
    }
    __syncthreads();
    #pragma unroll
    for (int kk = 0; kk < BK; kk += 32) {
      s16x8 af[MR], bf[NR];
      #pragma unroll
      for (int i = 0; i < MR; i++)
        af[i] = *(const s16x8*)(&As[(wr * WSM + i * 16 + fr) * LSTR + kk + fq * 8]);
      #pragma unroll
      for (int j = 0; j < NR; j++)
        bf[j] = *(const s16x8*)(&Ws[(wc * WSN + j * 16 + fr) * LSTR + kk + fq * 8]);
      #pragma unroll
      for (int i = 0; i < MR; i++)
        #pragma unroll
        for (int j = 0; j < NR; j++)
          acc[i][j] = __builtin_amdgcn_mfma_f32_16x16x32_bf16(af[i], bf[j], acc[i][j], 0, 0, 0);
    }
    __syncthreads();
  }

  #pragma unroll
  for (int i = 0; i < MR; i++) {
    const int mbase = tileM + wr * WSM + i * 16 + fq * 4;
    #pragma unroll
    for (int j = 0; j < NR; j++) {
      const int n = tileN + wc * WSN + j * 16 + fr;
      const float bv = bias ? bias[n] : 0.f;
      if constexpr (TRANS) {
        ushort4 o;
        o.x = f2bf(acc[i][j][0] * alpha + bv);
        o.y = f2bf(acc[i][j][1] * alpha + bv);
        o.z = f2bf(acc[i][j][2] * alpha + bv);
        o.w = f2bf(acc[i][j][3] * alpha + bv);
        *(ushort4*)((unsigned short*)C + (long)n * TM + mbase) = o;
      } else {
        #pragma unroll
        for (int q = 0; q < 4; q++) {
          float v = acc[i][j][q] * alpha + bv;
          if constexpr (sizeof(CT) == 2)
            C[(long)(mbase + q) * N + n] = f2bf(v);
          else
            C[(long)(mbase + q) * N + n] = v;
        }
      }
    }
  }
}

// ---------------- softmax over k (64 slots) per column m, in place ----------------
__global__ __launch_bounds__(256) void softmax_col_k(float* __restrict__ sc) {
  const int b = blockIdx.y;
  const int m = blockIdx.x * 256 + threadIdx.x;
  const long base = (long)b * 64 * 4096 + m;
  float v[64];
  #pragma unroll
  for (int k = 0; k < 64; k++) v[k] = sc[base + (long)k * 4096];
  float mx = v[0];
  #pragma unroll
  for (int k = 1; k < 64; k++) mx = fmaxf(mx, v[k]);
  float s = 0.f;
  #pragma unroll
  for (int k = 0; k < 64; k++) {
    v[k] = __expf(v[k] - mx);
    s += v[k];
  }
  float inv = 1.f / s;
  #pragma unroll
  for (int k = 0; k < 64; k++) sc[base + (long)k * 4096] = v[k] * inv;
}

// ---------------- per-(b,k) row sum over m=4096 (deterministic) ----------------
__global__ __launch_bounds__(256) void row_sum_k(const float* __restrict__ a,
                                                 float* __restrict__ out) {
  const int row = blockIdx.x;  // 0..511
  const int tid = threadIdx.x;
  const float4* p = (const float4*)(a + (long)row * 4096);
  float s = 0.f;
  #pragma unroll
  for (int i = 0; i < 4; i++) {
    float4 t = p[tid + i * 256];
    s += t.x + t.y + t.z + t.w;
  }
  #pragma unroll
  for (int off = 32; off; off >>= 1) s += __shfl_xor(s, off, 64);
  __shared__ float sb[4];
  if ((tid & 63) == 0) sb[tid >> 6] = s;
  __syncthreads();
  if (tid == 0) out[row] = sb[0] + sb[1] + sb[2] + sb[3];
}

// ---------------- attn / (rowsum + eps) -> bf16 ----------------
__global__ __launch_bounds__(256) void attn_norm_k(const float* __restrict__ a,
                                                   const float* __restrict__ rowsum,
                                                   unsigned short* __restrict__ out) {
  long i = (long)blockIdx.x * 256 + threadIdx.x;  // one 8-elem chunk
  int row = (int)(i >> 9);                        // 4096/8 = 512 chunks per row
  float inv = 1.f / (rowsum[row] + 1e-6f);
  const float4* p = (const float4*)a;
  float4 x = p[i * 2], y = p[i * 2 + 1];
  ushort4 lo, hi;
  lo.x = f2bf(x.x * inv); lo.y = f2bf(x.y * inv); lo.z = f2bf(x.z * inv); lo.w = f2bf(x.w * inv);
  hi.x = f2bf(y.x * inv); hi.y = f2bf(y.y * inv); hi.z = f2bf(y.z * inv); hi.w = f2bf(y.w * inv);
  ushort4* o = (ushort4*)out;
  o[i * 2] = lo;
  o[i * 2 + 1] = hi;
}

// ---------------- GRU combine (elementwise, fp32) ----------------
__global__ __launch_bounds__(256) void gru_k(const float* __restrict__ gi,
                                             const float* __restrict__ gh,
                                             const float* __restrict__ h,
                                             float* __restrict__ out) {
  int t = blockIdx.x * 256 + threadIdx.x;  // 0..131071, 4 elems each
  int r = t >> 8;
  int c = (t & 255) * 4;
  long gb = (long)r * 3072 + c;
  float4 ir = *(const float4*)(gi + gb);
  float4 iz = *(const float4*)(gi + gb + 1024);
  float4 in = *(const float4*)(gi + gb + 2048);
  float4 hr = *(const float4*)(gh + gb);
  float4 hz = *(const float4*)(gh + gb + 1024);
  float4 hn = *(const float4*)(gh + gb + 2048);
  float4 hv = *(const float4*)(h + (long)r * 1024 + c);
  float4 o;
  {
    float rr = sigm(ir.x + hr.x), zz = sigm(iz.x + hz.x);
    float nn = tanhf(in.x + rr * hn.x);
    o.x = (1.f - zz) * nn + zz * hv.x;
  }
  {
    float rr = sigm(ir.y + hr.y), zz = sigm(iz.y + hz.y);
    float nn = tanhf(in.y + rr * hn.y);
    o.y = (1.f - zz) * nn + zz * hv.y;
  }
  {
    float rr = sigm(ir.z + hr.z), zz = sigm(iz.z + hz.z);
    float nn = tanhf(in.z + rr * hn.z);
    o.z = (1.f - zz) * nn + zz * hv.z;
  }
  {
    float rr = sigm(ir.w + hr.w), zz = sigm(iz.w + hz.w);
    float nn = tanhf(in.w + rr * hn.w);
    o.w = (1.f - zz) * nn + zz * hv.w;
  }
  *(float4*)(out + (long)r * 1024 + c) = o;
}

extern "C" void kernel_launch(void* const* d_in, const int* in_sizes, int n_in,
                              void* d_out, int out_size, void* d_ws, size_t ws_size,
                              hipStream_t stream) {
  const float* slots_in = (const float*)d_in[0];
  const float* P        = (const float*)d_in[1];
  const float* Wq       = (const float*)d_in[2];
  const float* Wk       = (const float*)d_in[3];
  const float* Wv       = (const float*)d_in[4];
  const float* wi       = (const float*)d_in[5];
  const float* wh       = (const float*)d_in[6];
  const float* bi       = (const float*)d_in[7];
  const float* bh       = (const float*)d_in[8];
  const float* snw      = (const float*)d_in[9];
  const float* inw      = (const float*)d_in[10];

  const size_t MB = 1024ull * 1024ull;
  char* ws = (char*)d_ws;
  unsigned short* kproj = (unsigned short*)(ws + 0);        // 64MB  [b][m][e] bf16
  unsigned short* vt    = (unsigned short*)(ws + 64 * MB);  // 64MB  [b][e][m] bf16
  char* S               = ws + 128 * MB;                    // 64MB reuse region
  unsigned short* Pn    = (unsigned short*)(S);             // prologue only
  unsigned short* sn    = (unsigned short*)(S);             // 1MB
  unsigned short* qb    = (unsigned short*)(S + 1 * MB);    // 1MB
  float* scores         = (float*)(S + 2 * MB);             // 8MB
  unsigned short* attnb = (unsigned short*)(S + 10 * MB);   // 4MB
  unsigned short* updb  = (unsigned short*)(S + 14 * MB);   // 1MB
  unsigned short* slotsb= (unsigned short*)(S + 15 * MB);   // 1MB
  float* gi             = (float*)(S + 16 * MB);            // 6MB
  float* gh             = (float*)(S + 22 * MB);            // 6MB
  unsigned short* wq_b  = (unsigned short*)(S + 28 * MB);   // 2MB (written after prologue)
  unsigned short* wi_b  = (unsigned short*)(S + 30 * MB);   // 6MB
  unsigned short* wh_b  = (unsigned short*)(S + 36 * MB);   // 6MB
  unsigned short* wk_b  = (unsigned short*)(ws + 192 * MB); // 2MB
  unsigned short* wv_b  = (unsigned short*)(ws + 194 * MB); // 2MB
  float* slots          = (float*)(ws + 196 * MB);          // 2MB
  float* rowsum         = (float*)(ws + 198 * MB);          // 2KB

  auto cvt = [&](const float* in, unsigned short* out, long n) {
    long n8 = n / 8;
    cvt_bf16_k<<<dim3((unsigned)((n8 + 255) / 256)), 256, 0, stream>>>(in, out, n8);
  };

  // ---- prologue: K/V projections of rmsnorm(P) ----
  cvt(Wk, wk_b, 1024L * 1024);
  cvt(Wv, wv_b, 1024L * 1024);
  rmsnorm_k<<<32768, 256, 0, stream>>>(P, inw, Pn);
  // k_proj[b][m][e], batched over b: M=4096, N=1024, K=1024
  gemm_bt<128, 128, 2, 2, unsigned short, false>
      <<<dim3(8, 32, 8), 256, 0, stream>>>(Pn, wk_b, kproj, 4096, 1024, 1024,
                                           4096L * 1024, 0, 4096L * 1024, nullptr, 1.f, 0);
  // v_t[b][e][m] (transposed store): M=4096, N=1024, K=1024
  gemm_bt<128, 128, 2, 2, unsigned short, true>
      <<<dim3(8, 32, 8), 256, 0, stream>>>(Pn, wv_b, vt, 4096, 1024, 1024,
                                           4096L * 1024, 0, 1024L * 4096, nullptr, 1.f, 4096);
  // remaining weights (into the region Pn occupied — Pn is dead now)
  cvt(Wq, wq_b, 1024L * 1024);
  cvt(wi, wi_b, 3072L * 1024);
  cvt(wh, wh_b, 3072L * 1024);
  hipMemcpyAsync(slots, slots_in, 512L * 1024 * 4, hipMemcpyDeviceToDevice, stream);

  // ---- 3 iterations ----
  for (int it = 0; it < 3; ++it) {
    rmsnorm_k<<<512, 256, 0, stream>>>(slots, snw, sn);
    // q = sn @ Wq^T : M=512, N=1024, K=1024
    gemm_bt<64, 64, 2, 2, unsigned short, false>
        <<<dim3(16, 8, 1), 256, 0, stream>>>(sn, wq_b, qb, 512, 1024, 1024,
                                             0, 0, 0, nullptr, 1.f, 0);
    // scores[b][k][m] = (q_b @ kproj_b^T)/32 : M=64, N=4096, K=1024, batch 8
    gemm_bt<64, 128, 1, 4, float, false>
        <<<dim3(32, 1, 8), 256, 0, stream>>>(qb, kproj, scores, 64, 4096, 1024,
                                             64L * 1024, 4096L * 1024, 64L * 4096,
                                             nullptr, 0.03125f, 0);
    softmax_col_k<<<dim3(16, 8), 256, 0, stream>>>(scores);
    row_sum_k<<<512, 256, 0, stream>>>(scores, rowsum);
    attn_norm_k<<<1024, 256, 0, stream>>>(scores, rowsum, attnb);
    // updates[b][k][d] = attn_b @ vt_b^T : M=64, N=1024, K=4096, batch 8
    gemm_bt<64, 64, 2, 2, unsigned short, false>
        <<<dim3(16, 1, 8), 256, 0, stream>>>(attnb, vt, updb, 64, 1024, 4096,
                                             64L * 4096, 1024L * 4096, 64L * 1024,
                                             nullptr, 1.f, 0);
    cvt(slots, slotsb, 512L * 1024);
    // gi = updates @ wi^T + bi : M=512, N=3072, K=1024
    gemm_bt<64, 64, 2, 2, float, false>
        <<<dim3(48, 8, 1), 256, 0, stream>>>(updb, wi_b, gi, 512, 3072, 1024,
                                             0, 0, 0, bi, 1.f, 0);
    // gh = slots @ wh^T + bh
    gemm_bt<64, 64, 2, 2, float, false>
        <<<dim3(48, 8, 1), 256, 0, stream>>>(slotsb, wh_b, gh, 512, 3072, 1024,
                                             0, 0, 0, bh, 1.f, 0);
    float* dst = (it == 2) ? (float*)d_out : slots;
    gru_k<<<512, 256, 0, stream>>>(gi, gh, slots, dst);
  }
}

// Round 2
// 628.563 us; speedup vs baseline: 1.4674x; 1.4674x over previous
//
#include <hip/hip_runtime.h>

typedef __attribute__((ext_vector_type(4))) float f32x4;
typedef __attribute__((ext_vector_type(8))) short s16x8;

static __device__ __forceinline__ unsigned short f2bf(float f) {
  unsigned int u = __builtin_bit_cast(unsigned int, f);
  u += 0x7fffu + ((u >> 16) & 1u);
  return (unsigned short)(u >> 16);
}
static __device__ __forceinline__ float sigm(float x) { return 1.0f / (1.0f + __expf(-x)); }

// async global->LDS, 16B per lane. LDS dest = wave-uniform base + lane*16.
static __device__ __forceinline__ void gload16(const unsigned short* g, unsigned short* l) {
  __builtin_amdgcn_global_load_lds(
      (const __attribute__((address_space(1))) void*)g,
      (__attribute__((address_space(3))) void*)l, 16, 0, 0);
}

// ---------------- rmsnorm rows of length 1024: fp32 -> bf16 ----------------
__global__ __launch_bounds__(256) void rmsnorm_k(const float* __restrict__ x,
                                                 const float* __restrict__ w,
                                                 unsigned short* __restrict__ y) {
  const int row = blockIdx.x;
  const int tid = threadIdx.x;
  const float4* xp = (const float4*)(x + (long)row * 1024);
  float4 v = xp[tid];
  float ss = v.x * v.x + v.y * v.y + v.z * v.z + v.w * v.w;
  #pragma unroll
  for (int off = 32; off; off >>= 1) ss += __shfl_xor(ss, off, 64);
  __shared__ float sb[4];
  if ((tid & 63) == 0) sb[tid >> 6] = ss;
  __syncthreads();
  float tot = sb[0] + sb[1] + sb[2] + sb[3];
  float rs = rsqrtf(tot * (1.0f / 1024.0f) + 1e-6f);
  const float4* wp = (const float4*)w;
  float4 wv = wp[tid];
  ushort4 o;
  o.x = f2bf(v.x * rs * wv.x);
  o.y = f2bf(v.y * rs * wv.y);
  o.z = f2bf(v.z * rs * wv.z);
  o.w = f2bf(v.w * rs * wv.w);
  ((ushort4*)y)[(long)row * 256 + tid] = o;
}

// ---------------- fp32 -> bf16 convert (8 elems/thread) ----------------
__global__ __launch_bounds__(256) void cvt_bf16_k(const float* __restrict__ in,
                                                  unsigned short* __restrict__ out,
                                                  long n8) {
  long i = (long)blockIdx.x * 256 + threadIdx.x;
  if (i >= n8) return;
  const float4* p = (const float4*)in;
  float4 a = p[i * 2], b = p[i * 2 + 1];
  ushort4 lo, hi;
  lo.x = f2bf(a.x); lo.y = f2bf(a.y); lo.z = f2bf(a.z); lo.w = f2bf(a.w);
  hi.x = f2bf(b.x); hi.y = f2bf(b.y); hi.z = f2bf(b.z); hi.w = f2bf(b.w);
  ushort4* o = (ushort4*)out;
  o[i * 2] = lo;
  o[i * 2 + 1] = hi;
}

// ---------------- GEMM: C = alpha * A[M][K] @ W[N][K]^T (+bias) ----------------
// m97 structure: linear LDS [rows][64], global_load_lds width-16 staging.
// EPI: 0 = plain store (CT float or bf16, +bias, *alpha)
//      1 = transposed bf16 store C[n*TM + m]
//      2 = softmax over M (=64, WR==1) -> bf16 attn + per-wave row partial sums
// SPLIT: K-split batching; blockIdx.z = zb*SPLIT + zs, A/W advance zs*Klen cols.
template <int BM, int BN, int WR, int WC, typename CT, int EPI, int SPLIT>
__global__ __launch_bounds__(WR * WC * 64) void gemm_bt(
    const unsigned short* __restrict__ A, const unsigned short* __restrict__ W,
    CT* __restrict__ C, int N, int Klen, int lda, int ldw,
    long sA, long sW, long sC, const float* __restrict__ bias,
    float alpha, int TM, float* __restrict__ rs_part) {
  constexpr int BK = 64;
  constexpr int NT = WR * WC * 64;
  static_assert(NT == 256, "256 threads");
  constexpr int WSM = BM / WR, WSN = BN / WC;
  constexpr int MR = WSM / 16, NR = WSN / 16;
  constexpr int SEG_A = BM / 8, SEG_W = BN / 8;  // 1KB segments (8 rows x 128B)
  constexpr int PA = SEG_A / 4, PW = SEG_W / 4;
  static_assert(SEG_A % 4 == 0 && SEG_W % 4 == 0, "seg divisibility");
  __shared__ unsigned short As[BM * BK];
  __shared__ unsigned short Ws[BN * BK];
  const int tid = threadIdx.x, lane = tid & 63, wid = tid >> 6;
  const int wr = wid / WC, wc = wid % WC;
  const int tileN = blockIdx.x * BN, tileM = blockIdx.y * BM;
  const int zb = blockIdx.z / SPLIT, zs = blockIdx.z % SPLIT;
  A += (long)zb * sA + (long)zs * Klen;
  W += (long)zb * sW + (long)zs * Klen;
  C += (long)blockIdx.z * sC;
  const int srow = lane >> 3;        // row within 8-row segment
  const int scol = (lane & 7) * 8;   // elem col within row
  f32x4 acc[MR][NR];
  #pragma unroll
  for (int i = 0; i < MR; i++)
    #pragma unroll
    for (int j = 0; j < NR; j++) acc[i][j] = (f32x4){0.f, 0.f, 0.f, 0.f};
  const int fr = lane & 15, fq = lane >> 4;

  for (int k0 = 0; k0 < Klen; k0 += BK) {
    #pragma unroll
    for (int p = 0; p < PA; p++) {
      int seg = wid * PA + p;
      gload16(A + (long)(tileM + seg * 8 + srow) * lda + k0 + scol, &As[seg * 512]);
    }
    #pragma unroll
    for (int p = 0; p < PW; p++) {
      int seg = wid * PW + p;
      gload16(W + (long)(tileN + seg * 8 + srow) * ldw + k0 + scol, &Ws[seg * 512]);
    }
    __syncthreads();
    #pragma unroll
    for (int kk = 0; kk < BK; kk += 32) {
      s16x8 af[MR], bf[NR];
      #pragma unroll
      for (int i = 0; i < MR; i++)
        af[i] = *(const s16x8*)(&As[(wr * WSM + i * 16 + fr) * BK + kk + fq * 8]);
      #pragma unroll
      for (int j = 0; j < NR; j++)
        bf[j] = *(const s16x8*)(&Ws[(wc * WSN + j * 16 + fr) * BK + kk + fq * 8]);
      #pragma unroll
      for (int i = 0; i < MR; i++)
        #pragma unroll
        for (int j = 0; j < NR; j++)
          acc[i][j] = __builtin_amdgcn_mfma_f32_16x16x32_bf16(af[i], bf[j], acc[i][j], 0, 0, 0);
    }
    __syncthreads();
  }

  if constexpr (EPI == 2) {
    static_assert(WR == 1 && BM == 64, "softmax epilogue needs full-M wave");
    // scale
    #pragma unroll
    for (int i = 0; i < MR; i++)
      #pragma unroll
      for (int j = 0; j < NR; j++)
        #pragma unroll
        for (int q = 0; q < 4; q++) acc[i][j][q] *= alpha;
    // softmax over the 64-row column (4 fq lanes x 16 in-reg values)
    float inv[NR];
    #pragma unroll
    for (int j = 0; j < NR; j++) {
      float mx = -1e30f;
      #pragma unroll
      for (int i = 0; i < MR; i++)
        #pragma unroll
        for (int q = 0; q < 4; q++) mx = fmaxf(mx, acc[i][j][q]);
      mx = fmaxf(mx, __shfl_xor(mx, 16, 64));
      mx = fmaxf(mx, __shfl_xor(mx, 32, 64));
      float sm = 0.f;
      #pragma unroll
      for (int i = 0; i < MR; i++)
        #pragma unroll
        for (int q = 0; q < 4; q++) {
          float e = __expf(acc[i][j][q] - mx);
          acc[i][j][q] = e;
          sm += e;
        }
      sm += __shfl_xor(sm, 16, 64);
      sm += __shfl_xor(sm, 32, 64);
      inv[j] = 1.f / sm;
    }
    // write bf16 attn + accumulate row partials over this wave's 32 columns
    float rp[MR][4];
    #pragma unroll
    for (int i = 0; i < MR; i++)
      #pragma unroll
      for (int q = 0; q < 4; q++) rp[i][q] = 0.f;
    unsigned short* Cs = (unsigned short*)C;
    #pragma unroll
    for (int i = 0; i < MR; i++)
      #pragma unroll
      for (int j = 0; j < NR; j++)
        #pragma unroll
        for (int q = 0; q < 4; q++) {
          float a = acc[i][j][q] * inv[j];
          rp[i][q] += a;
          Cs[(long)(i * 16 + fq * 4 + q) * N + tileN + wc * WSN + j * 16 + fr] = f2bf(a);
        }
    #pragma unroll
    for (int off = 1; off <= 8; off <<= 1)
      #pragma unroll
      for (int i = 0; i < MR; i++)
        #pragma unroll
        for (int q = 0; q < 4; q++) rp[i][q] += __shfl_xor(rp[i][q], off, 64);
    if (fr == 0) {
      const int rld = gridDim.x * WC;
      #pragma unroll
      for (int i = 0; i < MR; i++)
        #pragma unroll
        for (int q = 0; q < 4; q++)
          rs_part[((long)zb * 64 + i * 16 + fq * 4 + q) * rld + blockIdx.x * WC + wc] = rp[i][q];
    }
    return;
  }

  #pragma unroll
  for (int i = 0; i < MR; i++) {
    const int mbase = tileM + wr * WSM + i * 16 + fq * 4;
    #pragma unroll
    for (int j = 0; j < NR; j++) {
      const int n = tileN + wc * WSN + j * 16 + fr;
      if constexpr (EPI == 1) {
        ushort4 o;
        o.x = f2bf(acc[i][j][0]);
        o.y = f2bf(acc[i][j][1]);
        o.z = f2bf(acc[i][j][2]);
        o.w = f2bf(acc[i][j][3]);
        *(ushort4*)((unsigned short*)C + (long)n * TM + mbase) = o;
      } else {
        const float bv = bias ? bias[n] : 0.f;
        #pragma unroll
        for (int q = 0; q < 4; q++) {
          float v = acc[i][j][q] * alpha + bv;
          if constexpr (sizeof(CT) == 2)
            C[(long)(mbase + q) * N + n] = f2bf(v);
          else
            C[(long)(mbase + q) * N + n] = v;
        }
      }
    }
  }
}

// ---------------- rowsum finalize: rowinv[r] = 1/(sum(rs_part[r][:]) + eps) ----------------
__global__ __launch_bounds__(256) void rowinv_k(const float* __restrict__ rs_part,
                                                float* __restrict__ rowinv, int ld) {
  int r = blockIdx.x * 256 + threadIdx.x;
  if (r >= 512) return;
  const float* p = rs_part + (long)r * ld;
  float s = 0.f;
  for (int i = 0; i < ld; i++) s += p[i];
  rowinv[r] = 1.f / (s + 1e-6f);
}

// ---------------- reduce 4 K-splits, scale rows by rowinv, cast bf16 ----------------
__global__ __launch_bounds__(256) void upd_reduce_k(const float* __restrict__ part,
                                                    const float* __restrict__ rowinv,
                                                    unsigned short* __restrict__ out) {
  long t = (long)blockIdx.x * 256 + threadIdx.x;  // 131072 threads, 4 elems each
  long e = t * 4;
  int b = (int)(e >> 16);
  int k = (int)((e >> 10) & 63);
  const float* base = part + (long)b * 4 * 65536 + (e & 65535);
  float4 s = {0.f, 0.f, 0.f, 0.f};
  #pragma unroll
  for (int sp = 0; sp < 4; sp++) {
    float4 v = *(const float4*)(base + (long)sp * 65536);
    s.x += v.x; s.y += v.y; s.z += v.z; s.w += v.w;
  }
  float inv = rowinv[b * 64 + k];
  ushort4 o;
  o.x = f2bf(s.x * inv); o.y = f2bf(s.y * inv); o.z = f2bf(s.z * inv); o.w = f2bf(s.w * inv);
  ((ushort4*)out)[t] = o;
}

// ---------------- GRU combine (elementwise, fp32 + bf16 out) ----------------
__global__ __launch_bounds__(256) void gru_k(const float* __restrict__ gi,
                                             const float* __restrict__ gh,
                                             const float* __restrict__ h,
                                             float* __restrict__ out,
                                             unsigned short* __restrict__ out_bf) {
  int t = blockIdx.x * 256 + threadIdx.x;  // 131072, 4 elems each
  int r = t >> 8;
  int c = (t & 255) * 4;
  long gb = (long)r * 3072 + c;
  float4 ir = *(const float4*)(gi + gb);
  float4 iz = *(const float4*)(gi + gb + 1024);
  float4 in = *(const float4*)(gi + gb + 2048);
  float4 hr = *(const float4*)(gh + gb);
  float4 hz = *(const float4*)(gh + gb + 1024);
  float4 hn = *(const float4*)(gh + gb + 2048);
  float4 hv = *(const float4*)(h + (long)r * 1024 + c);
  float4 o;
  {
    float rr = sigm(ir.x + hr.x), zz = sigm(iz.x + hz.x);
    float nn = tanhf(in.x + rr * hn.x);
    o.x = (1.f - zz) * nn + zz * hv.x;
  }
  {
    float rr = sigm(ir.y + hr.y), zz = sigm(iz.y + hz.y);
    float nn = tanhf(in.y + rr * hn.y);
    o.y = (1.f - zz) * nn + zz * hv.y;
  }
  {
    float rr = sigm(ir.z + hr.z), zz = sigm(iz.z + hz.z);
    float nn = tanhf(in.z + rr * hn.z);
    o.z = (1.f - zz) * nn + zz * hv.z;
  }
  {
    float rr = sigm(ir.w + hr.w), zz = sigm(iz.w + hz.w);
    float nn = tanhf(in.w + rr * hn.w);
    o.w = (1.f - zz) * nn + zz * hv.w;
  }
  *(float4*)(out + (long)r * 1024 + c) = o;
  ushort4 ob;
  ob.x = f2bf(o.x); ob.y = f2bf(o.y); ob.z = f2bf(o.z); ob.w = f2bf(o.w);
  *(ushort4*)(out_bf + (long)r * 1024 + c) = ob;
}

extern "C" void kernel_launch(void* const* d_in, const int* in_sizes, int n_in,
                              void* d_out, int out_size, void* d_ws, size_t ws_size,
                              hipStream_t stream) {
  const float* slots_in = (const float*)d_in[0];
  const float* P        = (const float*)d_in[1];
  const float* Wq       = (const float*)d_in[2];
  const float* Wk       = (const float*)d_in[3];
  const float* Wv       = (const float*)d_in[4];
  const float* wi       = (const float*)d_in[5];
  const float* wh       = (const float*)d_in[6];
  const float* bi       = (const float*)d_in[7];
  const float* bh       = (const float*)d_in[8];
  const float* snw      = (const float*)d_in[9];
  const float* inw      = (const float*)d_in[10];

  const size_t MB = 1024ull * 1024ull;
  char* ws = (char*)d_ws;
  unsigned short* kproj = (unsigned short*)(ws + 0);        // 64MB [b][m][e] bf16
  unsigned short* vt    = (unsigned short*)(ws + 64 * MB);  // 64MB [b][e][m] bf16
  char* S               = ws + 128 * MB;                    // 64MB reuse region
  unsigned short* Pn    = (unsigned short*)(S);             // prologue only (64MB)
  unsigned short* sn    = (unsigned short*)(S);             // 1MB
  unsigned short* qb    = (unsigned short*)(S + 1 * MB);    // 1MB
  unsigned short* attnb = (unsigned short*)(S + 2 * MB);    // 4MB
  unsigned short* updb  = (unsigned short*)(S + 6 * MB);    // 1MB
  unsigned short* slotsb= (unsigned short*)(S + 7 * MB);    // 1MB
  float* gi             = (float*)(S + 8 * MB);             // 6MB
  float* gh             = (float*)(S + 14 * MB);            // 6MB
  float* Cpart          = (float*)(S + 20 * MB);            // 8MB [b*4+s][64][1024]
  float* rs_part        = (float*)(S + 28 * MB);            // 256KB [b][64][128]
  float* rowinv         = (float*)(S + 29 * MB);            // 2KB
  unsigned short* wq_b  = (unsigned short*)(S + 30 * MB);   // 2MB (written post-prologue)
  unsigned short* wi_b  = (unsigned short*)(S + 32 * MB);   // 6MB
  unsigned short* wh_b  = (unsigned short*)(S + 38 * MB);   // 6MB
  unsigned short* wk_b  = (unsigned short*)(ws + 192 * MB); // 2MB
  unsigned short* wv_b  = (unsigned short*)(ws + 194 * MB); // 2MB
  float* slots          = (float*)(ws + 196 * MB);          // 2MB

  auto cvt = [&](const float* in, unsigned short* out, long n) {
    long n8 = n / 8;
    cvt_bf16_k<<<dim3((unsigned)((n8 + 255) / 256)), 256, 0, stream>>>(in, out, n8);
  };

  // ---- prologue ----
  cvt(Wk, wk_b, 1024L * 1024);
  cvt(Wv, wv_b, 1024L * 1024);
  rmsnorm_k<<<32768, 256, 0, stream>>>(P, inw, Pn);
  // k_proj[b][m][e]: M=4096, N=1024, K=1024, batch 8
  gemm_bt<128, 128, 2, 2, unsigned short, 0, 1>
      <<<dim3(8, 32, 8), 256, 0, stream>>>(Pn, wk_b, kproj, 1024, 1024, 1024, 1024,
                                           4096L * 1024, 0, 4096L * 1024, nullptr, 1.f, 0, nullptr);
  // v_t[b][e][m] (transposed store)
  gemm_bt<128, 128, 2, 2, unsigned short, 1, 1>
      <<<dim3(8, 32, 8), 256, 0, stream>>>(Pn, wv_b, vt, 1024, 1024, 1024, 1024,
                                           4096L * 1024, 0, 1024L * 4096, nullptr, 1.f, 4096, nullptr);
  // remaining weights (Pn region is dead after the projections)
  cvt(Wq, wq_b, 1024L * 1024);
  cvt(wi, wi_b, 3072L * 1024);
  cvt(wh, wh_b, 3072L * 1024);
  hipMemcpyAsync(slots, slots_in, 512L * 1024 * 4, hipMemcpyDeviceToDevice, stream);
  cvt(slots_in, slotsb, 512L * 1024);

  // ---- 3 iterations ----
  for (int it = 0; it < 3; ++it) {
    rmsnorm_k<<<512, 256, 0, stream>>>(slots, snw, sn);
    // q = sn @ Wq^T : M=512, N=1024, K=1024
    gemm_bt<64, 64, 2, 2, unsigned short, 0, 1>
        <<<dim3(16, 8, 1), 256, 0, stream>>>(sn, wq_b, qb, 1024, 1024, 1024, 1024,
                                             0, 0, 0, nullptr, 1.f, 0, nullptr);
    // attn[b][k][m] = softmax_k((q_b @ kproj_b^T)/32), + row partial sums
    gemm_bt<64, 128, 1, 4, unsigned short, 2, 1>
        <<<dim3(32, 1, 8), 256, 0, stream>>>(qb, kproj, attnb, 4096, 1024, 1024, 1024,
                                             64L * 1024, 4096L * 1024, 64L * 4096,
                                             nullptr, 0.03125f, 0, rs_part);
    rowinv_k<<<2, 256, 0, stream>>>(rs_part, rowinv, 32 * 4);
    // updates partials: attn_b @ vt_b^T, K=4096 split 4x1024 : 512 blocks
    gemm_bt<64, 64, 2, 2, float, 0, 4>
        <<<dim3(16, 1, 32), 256, 0, stream>>>(attnb, vt, Cpart, 1024, 1024, 4096, 4096,
                                              64L * 4096, 1024L * 4096, 64L * 1024,
                                              nullptr, 1.f, 0, nullptr);
    upd_reduce_k<<<512, 256, 0, stream>>>(Cpart, rowinv, updb);
    // gi = updates @ wi^T + bi : M=512, N=3072, K=1024
    gemm_bt<64, 64, 2, 2, float, 0, 1>
        <<<dim3(48, 8, 1), 256, 0, stream>>>(updb, wi_b, gi, 3072, 1024, 1024, 1024,
                                             0, 0, 0, bi, 1.f, 0, nullptr);
    // gh = slots @ wh^T + bh
    gemm_bt<64, 64, 2, 2, float, 0, 1>
        <<<dim3(48, 8, 1), 256, 0, stream>>>(slotsb, wh_b, gh, 3072, 1024, 1024, 1024,
                                             0, 0, 0, bh, 1.f, 0, nullptr);
    float* dst = (it == 2) ? (float*)d_out : slots;
    gru_k<<<512, 256, 0, stream>>>(gi, gh, slots, dst, slotsb);
  }
}

// Round 3
// 490.912 us; speedup vs baseline: 1.8788x; 1.2804x over previous
//
#include <hip/hip_runtime.h>

typedef __attribute__((ext_vector_type(4))) float f32x4;
typedef __attribute__((ext_vector_type(8))) short s16x8;

static __device__ __forceinline__ unsigned short f2bf(float f) {
  unsigned int u = __builtin_bit_cast(unsigned int, f);
  u += 0x7fffu + ((u >> 16) & 1u);
  return (unsigned short)(u >> 16);
}
static __device__ __forceinline__ float sigm(float x) { return 1.0f / (1.0f + __expf(-x)); }

// async global->LDS, 16B per lane. LDS dest = wave-uniform base + lane*16.
static __device__ __forceinline__ void gload16(const unsigned short* g, unsigned short* l) {
  __builtin_amdgcn_global_load_lds(
      (const __attribute__((address_space(1))) void*)g,
      (__attribute__((address_space(3))) void*)l, 16, 0, 0);
}

#define FENCE() asm volatile("" ::: "memory")
#define BAR()   { FENCE(); __builtin_amdgcn_s_barrier(); FENCE(); }
#define LGKM0() asm volatile("s_waitcnt lgkmcnt(0)" ::: "memory")

// ================= 8-phase 256^2 projection kernel =================
// C_full[32768][2048] = A[32768][1024] @ W[2048][1024]^T, epilogue splits:
//   n<1024  -> kproj[b][m][n]          (b = gm>>12, m = gm&4095)
//   n>=1024 -> vt[b][n-1024][m]        (transposed, ushort4 along m)
__global__ __launch_bounds__(512, 2) void proj_k(
    const unsigned short* __restrict__ A, const unsigned short* __restrict__ W,
    unsigned short* __restrict__ kproj, unsigned short* __restrict__ vt) {
  __shared__ unsigned short lds[2][2][2][8192];  // [buf][A/B][half][128*64]
  const int tid = threadIdx.x, lane = tid & 63, wid = tid >> 6;
  const int wm = wid >> 2, wn = wid & 3;
  // bijective XCD swizzle (nwg = 1024 = 8*128)
  const int wg = ((int)blockIdx.x & 7) * 128 + ((int)blockIdx.x >> 3);
  const int mt = wg >> 3, nt = wg & 7;
  const unsigned short* Ap = A + (long)mt * 256 * 1024;
  const unsigned short* Wp = W + (long)nt * 256 * 1024;
  // staging source (pre-swizzled so linear LDS + swizzled read = correct)
  const int srow = lane >> 3;                       // 0..7
  const int scol = (((lane & 7) ^ srow) << 3);      // swizzled short col
  const int fr = lane & 15, fq = lane >> 4;
  const int xorv = (fr & 7) << 3;                   // read-side XOR (shorts)

#define STAGE(buf, T, h, t)                                                    \
  { const unsigned short* gp_ = (T) ? Wp : Ap;                                 \
    _Pragma("unroll") for (int p = 0; p < 2; p++) {                            \
      int r_ = wid * 16 + p * 8 + srow;                                        \
      gload16(gp_ + (long)((h) * 128 + r_) * 1024 + (long)(t) * 64 + scol,     \
              &lds[buf][T][h][(wid * 2 + p) * 512]);                           \
    } }

#define LDA_FRAG(aq)                                                           \
  { _Pragma("unroll") for (int i = 0; i < 4; i++)                              \
      _Pragma("unroll") for (int kk = 0; kk < 2; kk++)                         \
        af[i * 2 + kk] = *(const s16x8*)(Ab + ((aq) * 64 + i * 16 + fr) * 64 + \
                                         ((kk * 32 + fq * 8) ^ xorv)); }

#define LDB_FRAG(bq, arr)                                                      \
  { _Pragma("unroll") for (int j = 0; j < 2; j++)                              \
      _Pragma("unroll") for (int kk = 0; kk < 2; kk++)                         \
        arr[j * 2 + kk] = *(const s16x8*)(Bb + ((wn & 1) * 64 + ((bq) * 2 + j) * 16 + fr) * 64 + \
                                          ((kk * 32 + fq * 8) ^ xorv)); }

#define MM_Q(aq, bq, arr)                                                      \
  { __builtin_amdgcn_s_setprio(1);                                             \
    _Pragma("unroll") for (int i = 0; i < 4; i++)                              \
      _Pragma("unroll") for (int j = 0; j < 2; j++)                            \
        _Pragma("unroll") for (int kk = 0; kk < 2; kk++)                       \
          acc[(aq) * 4 + i][(bq) * 2 + j] = __builtin_amdgcn_mfma_f32_16x16x32_bf16( \
              af[i * 2 + kk], arr[j * 2 + kk], acc[(aq) * 4 + i][(bq) * 2 + j], 0, 0, 0); \
    __builtin_amdgcn_s_setprio(0); }

  f32x4 acc[8][4];
  #pragma unroll
  for (int i = 0; i < 8; i++)
    #pragma unroll
    for (int j = 0; j < 4; j++) acc[i][j] = (f32x4){0.f, 0.f, 0.f, 0.f};

  // prologue: tile0 A0,A1,B0,B1 + tile1 B0,B1 (A(1) staged during tile0)
  STAGE(0, 0, 0, 0); STAGE(0, 0, 1, 0); STAGE(0, 1, 0, 0); STAGE(0, 1, 1, 0);
  STAGE(1, 1, 0, 1); STAGE(1, 1, 1, 1);
  asm volatile("s_waitcnt vmcnt(4)" ::: "memory");
  BAR();

  s16x8 af[8], b0f[4], b1f[4];
  for (int t = 0; t < 16; ++t) {
    const int pt = t & 1;
    const unsigned short* Ab = &lds[pt][0][wm][0];
    const unsigned short* Bb = &lds[pt][1][wn >> 1][0];
    // ---- phase 1: quadrant (0,0); stage A0(t+1) ----
    LDA_FRAG(0); LDB_FRAG(0, b0f);
    if (t < 15) STAGE(pt ^ 1, 0, 0, t + 1);
    BAR(); LGKM0();
    MM_Q(0, 0, b0f);
    BAR();
    // ---- phase 2: quadrant (0,1); stage A1(t+1) ----
    LDB_FRAG(1, b1f);
    if (t < 15) STAGE(pt ^ 1, 0, 1, t + 1);
    BAR(); LGKM0();
    MM_Q(0, 1, b1f);
    BAR();
    // ---- phase 3: quadrant (1,0); stage B0(t+2) ----
    LDA_FRAG(1);
    if (t < 14) STAGE(pt, 1, 0, t + 2);
    BAR(); LGKM0();
    MM_Q(1, 0, b0f);
    BAR();
    // ---- phase 4: quadrant (1,1); stage B1(t+2); counted vmcnt ----
    if (t < 14) STAGE(pt, 1, 1, t + 2);
    if (t == 14) { asm volatile("s_waitcnt vmcnt(0)" ::: "memory"); }
    else         { asm volatile("s_waitcnt vmcnt(4)" ::: "memory"); }
    BAR();
    MM_Q(1, 1, b1f);
    BAR();
  }

  // ---- epilogue: split K/V store ----
  const int nbase = nt * 256 + wn * 64;
  const bool kside = (nbase < 1024);
  #pragma unroll
  for (int i = 0; i < 8; i++) {
    const int gm0 = mt * 256 + wm * 128 + i * 16 + fq * 4;
    const int b = gm0 >> 12, mrow = gm0 & 4095;
    #pragma unroll
    for (int j = 0; j < 4; j++) {
      const int n = nbase + j * 16 + fr;
      if (kside) {
        unsigned short* dst = kproj + ((long)b * 4096 + mrow) * 1024 + n;
        #pragma unroll
        for (int q = 0; q < 4; q++) dst[(long)q * 1024] = f2bf(acc[i][j][q]);
      } else {
        ushort4 o;
        o.x = f2bf(acc[i][j][0]); o.y = f2bf(acc[i][j][1]);
        o.z = f2bf(acc[i][j][2]); o.w = f2bf(acc[i][j][3]);
        *(ushort4*)(vt + ((long)b * 1024 + (n - 1024)) * 4096 + mrow) = o;
      }
    }
  }
#undef STAGE
#undef LDA_FRAG
#undef LDB_FRAG
#undef MM_Q
}

// ---------------- rmsnorm rows of length 1024: fp32 -> bf16 ----------------
__global__ __launch_bounds__(256) void rmsnorm_k(const float* __restrict__ x,
                                                 const float* __restrict__ w,
                                                 unsigned short* __restrict__ y) {
  const int row = blockIdx.x;
  const int tid = threadIdx.x;
  const float4* xp = (const float4*)(x + (long)row * 1024);
  float4 v = xp[tid];
  float ss = v.x * v.x + v.y * v.y + v.z * v.z + v.w * v.w;
  #pragma unroll
  for (int off = 32; off; off >>= 1) ss += __shfl_xor(ss, off, 64);
  __shared__ float sb[4];
  if ((tid & 63) == 0) sb[tid >> 6] = ss;
  __syncthreads();
  float tot = sb[0] + sb[1] + sb[2] + sb[3];
  float rs = rsqrtf(tot * (1.0f / 1024.0f) + 1e-6f);
  const float4* wp = (const float4*)w;
  float4 wv = wp[tid];
  ushort4 o;
  o.x = f2bf(v.x * rs * wv.x);
  o.y = f2bf(v.y * rs * wv.y);
  o.z = f2bf(v.z * rs * wv.z);
  o.w = f2bf(v.w * rs * wv.w);
  ((ushort4*)y)[(long)row * 256 + tid] = o;
}

// ---------------- fp32 -> bf16 convert (8 elems/thread) ----------------
__global__ __launch_bounds__(256) void cvt_bf16_k(const float* __restrict__ in,
                                                  unsigned short* __restrict__ out,
                                                  long n8) {
  long i = (long)blockIdx.x * 256 + threadIdx.x;
  if (i >= n8) return;
  const float4* p = (const float4*)in;
  float4 a = p[i * 2], b = p[i * 2 + 1];
  ushort4 lo, hi;
  lo.x = f2bf(a.x); lo.y = f2bf(a.y); lo.z = f2bf(a.z); lo.w = f2bf(a.w);
  hi.x = f2bf(b.x); hi.y = f2bf(b.y); hi.z = f2bf(b.z); hi.w = f2bf(b.w);
  ushort4* o = (ushort4*)out;
  o[i * 2] = lo;
  o[i * 2 + 1] = hi;
}

// ---------------- GEMM: C = alpha * A[M][K] @ W[N][K]^T (+bias) ----------------
// EPI: 0 = plain store; 2 = softmax over M(=64) -> bf16 attn + row partials.
// SPLIT: K-split batching. bias2: used for odd blockIdx.z (merged gi/gh).
template <int BM, int BN, int WR, int WC, typename CT, int EPI, int SPLIT>
__global__ __launch_bounds__(WR * WC * 64) void gemm_bt(
    const unsigned short* __restrict__ A, const unsigned short* __restrict__ W,
    CT* __restrict__ C, int N, int Klen, int lda, int ldw,
    long sA, long sW, long sC, const float* __restrict__ bias,
    const float* __restrict__ bias2, float alpha, float* __restrict__ rs_part) {
  constexpr int BK = 64;
  constexpr int NT = WR * WC * 64;
  static_assert(NT == 256, "256 threads");
  constexpr int WSM = BM / WR, WSN = BN / WC;
  constexpr int MR = WSM / 16, NR = WSN / 16;
  constexpr int SEG_A = BM / 8, SEG_W = BN / 8;
  constexpr int PA = SEG_A / 4, PW = SEG_W / 4;
  static_assert(SEG_A % 4 == 0 && SEG_W % 4 == 0, "seg divisibility");
  __shared__ unsigned short As[BM * BK];
  __shared__ unsigned short Ws[BN * BK];
  const int tid = threadIdx.x, lane = tid & 63, wid = tid >> 6;
  const int wr = wid / WC, wc = wid % WC;
  const int tileN = blockIdx.x * BN, tileM = blockIdx.y * BM;
  const int zb = blockIdx.z / SPLIT, zs = blockIdx.z % SPLIT;
  A += (long)zb * sA + (long)zs * Klen;
  W += (long)zb * sW + (long)zs * Klen;
  C += (long)blockIdx.z * sC;
  const float* bp = (bias2 && (blockIdx.z & 1)) ? bias2 : bias;
  const int srow = lane >> 3;
  const int scol = (lane & 7) * 8;
  f32x4 acc[MR][NR];
  #pragma unroll
  for (int i = 0; i < MR; i++)
    #pragma unroll
    for (int j = 0; j < NR; j++) acc[i][j] = (f32x4){0.f, 0.f, 0.f, 0.f};
  const int fr = lane & 15, fq = lane >> 4;

  for (int k0 = 0; k0 < Klen; k0 += BK) {
    #pragma unroll
    for (int p = 0; p < PA; p++) {
      int seg = wid * PA + p;
      gload16(A + (long)(tileM + seg * 8 + srow) * lda + k0 + scol, &As[seg * 512]);
    }
    #pragma unroll
    for (int p = 0; p < PW; p++) {
      int seg = wid * PW + p;
      gload16(W + (long)(tileN + seg * 8 + srow) * ldw + k0 + scol, &Ws[seg * 512]);
    }
    __syncthreads();
    #pragma unroll
    for (int kk = 0; kk < BK; kk += 32) {
      s16x8 af[MR], bf[NR];
      #pragma unroll
      for (int i = 0; i < MR; i++)
        af[i] = *(const s16x8*)(&As[(wr * WSM + i * 16 + fr) * BK + kk + fq * 8]);
      #pragma unroll
      for (int j = 0; j < NR; j++)
        bf[j] = *(const s16x8*)(&Ws[(wc * WSN + j * 16 + fr) * BK + kk + fq * 8]);
      #pragma unroll
      for (int i = 0; i < MR; i++)
        #pragma unroll
        for (int j = 0; j < NR; j++)
          acc[i][j] = __builtin_amdgcn_mfma_f32_16x16x32_bf16(af[i], bf[j], acc[i][j], 0, 0, 0);
    }
    __syncthreads();
  }

  if constexpr (EPI == 2) {
    static_assert(WR == 1 && BM == 64, "softmax epilogue needs full-M wave");
    #pragma unroll
    for (int i = 0; i < MR; i++)
      #pragma unroll
      for (int j = 0; j < NR; j++)
        #pragma unroll
        for (int q = 0; q < 4; q++) acc[i][j][q] *= alpha;
    float inv[NR];
    #pragma unroll
    for (int j = 0; j < NR; j++) {
      float mx = -1e30f;
      #pragma unroll
      for (int i = 0; i < MR; i++)
        #pragma unroll
        for (int q = 0; q < 4; q++) mx = fmaxf(mx, acc[i][j][q]);
      mx = fmaxf(mx, __shfl_xor(mx, 16, 64));
      mx = fmaxf(mx, __shfl_xor(mx, 32, 64));
      float sm = 0.f;
      #pragma unroll
      for (int i = 0; i < MR; i++)
        #pragma unroll
        for (int q = 0; q < 4; q++) {
          float e = __expf(acc[i][j][q] - mx);
          acc[i][j][q] = e;
          sm += e;
        }
      sm += __shfl_xor(sm, 16, 64);
      sm += __shfl_xor(sm, 32, 64);
      inv[j] = 1.f / sm;
    }
    float rp[MR][4];
    #pragma unroll
    for (int i = 0; i < MR; i++)
      #pragma unroll
      for (int q = 0; q < 4; q++) rp[i][q] = 0.f;
    unsigned short* Cs = (unsigned short*)C;
    #pragma unroll
    for (int i = 0; i < MR; i++)
      #pragma unroll
      for (int j = 0; j < NR; j++)
        #pragma unroll
        for (int q = 0; q < 4; q++) {
          float a = acc[i][j][q] * inv[j];
          rp[i][q] += a;
          Cs[(long)(i * 16 + fq * 4 + q) * N + tileN + wc * WSN + j * 16 + fr] = f2bf(a);
        }
    #pragma unroll
    for (int off = 1; off <= 8; off <<= 1)
      #pragma unroll
      for (int i = 0; i < MR; i++)
        #pragma unroll
        for (int q = 0; q < 4; q++) rp[i][q] += __shfl_xor(rp[i][q], off, 64);
    if (fr == 0) {
      const int rld = gridDim.x * WC;
      #pragma unroll
      for (int i = 0; i < MR; i++)
        #pragma unroll
        for (int q = 0; q < 4; q++)
          rs_part[((long)zb * 64 + i * 16 + fq * 4 + q) * rld + blockIdx.x * WC + wc] = rp[i][q];
    }
    return;
  }

  #pragma unroll
  for (int i = 0; i < MR; i++) {
    const int mbase = tileM + wr * WSM + i * 16 + fq * 4;
    #pragma unroll
    for (int j = 0; j < NR; j++) {
      const int n = tileN + wc * WSN + j * 16 + fr;
      const float bv = bp ? bp[n] : 0.f;
      #pragma unroll
      for (int q = 0; q < 4; q++) {
        float v = acc[i][j][q] * alpha + bv;
        if constexpr (sizeof(CT) == 2)
          C[(long)(mbase + q) * N + n] = f2bf(v);
        else
          C[(long)(mbase + q) * N + n] = v;
      }
    }
  }
}

// ---------------- rowsum finalize ----------------
__global__ __launch_bounds__(256) void rowinv_k(const float* __restrict__ rs_part,
                                                float* __restrict__ rowinv, int ld) {
  int r = blockIdx.x * 256 + threadIdx.x;
  if (r >= 512) return;
  const float* p = rs_part + (long)r * ld;
  float s = 0.f;
  for (int i = 0; i < ld; i++) s += p[i];
  rowinv[r] = 1.f / (s + 1e-6f);
}

// ---------------- reduce 4 K-splits, scale by rowinv, cast bf16 ----------------
__global__ __launch_bounds__(256) void upd_reduce_k(const float* __restrict__ part,
                                                    const float* __restrict__ rowinv,
                                                    unsigned short* __restrict__ out) {
  long t = (long)blockIdx.x * 256 + threadIdx.x;
  long e = t * 4;
  int b = (int)(e >> 16);
  int k = (int)((e >> 10) & 63);
  const float* base = part + (long)b * 4 * 65536 + (e & 65535);
  float4 s = {0.f, 0.f, 0.f, 0.f};
  #pragma unroll
  for (int sp = 0; sp < 4; sp++) {
    float4 v = *(const float4*)(base + (long)sp * 65536);
    s.x += v.x; s.y += v.y; s.z += v.z; s.w += v.w;
  }
  float inv = rowinv[b * 64 + k];
  ushort4 o;
  o.x = f2bf(s.x * inv); o.y = f2bf(s.y * inv); o.z = f2bf(s.z * inv); o.w = f2bf(s.w * inv);
  ((ushort4*)out)[t] = o;
}

// ---------------- GRU combine (elementwise, fp32 + bf16 out) ----------------
__global__ __launch_bounds__(256) void gru_k(const float* __restrict__ gi,
                                             const float* __restrict__ gh,
                                             const float* __restrict__ h,
                                             float* __restrict__ out,
                                             unsigned short* __restrict__ out_bf) {
  int t = blockIdx.x * 256 + threadIdx.x;
  int r = t >> 8;
  int c = (t & 255) * 4;
  long gb = (long)r * 3072 + c;
  float4 ir = *(const float4*)(gi + gb);
  float4 iz = *(const float4*)(gi + gb + 1024);
  float4 in = *(const float4*)(gi + gb + 2048);
  float4 hr = *(const float4*)(gh + gb);
  float4 hz = *(const float4*)(gh + gb + 1024);
  float4 hn = *(const float4*)(gh + gb + 2048);
  float4 hv = *(const float4*)(h + (long)r * 1024 + c);
  float4 o;
  { float rr = sigm(ir.x + hr.x), zz = sigm(iz.x + hz.x);
    float nn = tanhf(in.x + rr * hn.x); o.x = (1.f - zz) * nn + zz * hv.x; }
  { float rr = sigm(ir.y + hr.y), zz = sigm(iz.y + hz.y);
    float nn = tanhf(in.y + rr * hn.y); o.y = (1.f - zz) * nn + zz * hv.y; }
  { float rr = sigm(ir.z + hr.z), zz = sigm(iz.z + hz.z);
    float nn = tanhf(in.z + rr * hn.z); o.z = (1.f - zz) * nn + zz * hv.z; }
  { float rr = sigm(ir.w + hr.w), zz = sigm(iz.w + hz.w);
    float nn = tanhf(in.w + rr * hn.w); o.w = (1.f - zz) * nn + zz * hv.w; }
  *(float4*)(out + (long)r * 1024 + c) = o;
  ushort4 ob;
  ob.x = f2bf(o.x); ob.y = f2bf(o.y); ob.z = f2bf(o.z); ob.w = f2bf(o.w);
  *(ushort4*)(out_bf + (long)r * 1024 + c) = ob;
}

extern "C" void kernel_launch(void* const* d_in, const int* in_sizes, int n_in,
                              void* d_out, int out_size, void* d_ws, size_t ws_size,
                              hipStream_t stream) {
  const float* slots_in = (const float*)d_in[0];
  const float* P        = (const float*)d_in[1];
  const float* Wq       = (const float*)d_in[2];
  const float* Wk       = (const float*)d_in[3];
  const float* Wv       = (const float*)d_in[4];
  const float* wi       = (const float*)d_in[5];
  const float* wh       = (const float*)d_in[6];
  const float* bi       = (const float*)d_in[7];
  const float* bh       = (const float*)d_in[8];
  const float* snw      = (const float*)d_in[9];
  const float* inw      = (const float*)d_in[10];

  const size_t MB = 1024ull * 1024ull;
  char* ws = (char*)d_ws;
  unsigned short* kproj = (unsigned short*)(ws + 0);        // 64MB [b][m][e] bf16
  unsigned short* vt    = (unsigned short*)(ws + 64 * MB);  // 64MB [b][e][m] bf16
  char* S               = ws + 128 * MB;                    // 64MB reuse region
  unsigned short* Pn    = (unsigned short*)(S);             // prologue only (64MB)
  unsigned short* sn    = (unsigned short*)(S);             // 1MB
  unsigned short* qb    = (unsigned short*)(S + 1 * MB);    // 1MB
  unsigned short* attnb = (unsigned short*)(S + 2 * MB);    // 4MB
  unsigned short* updb  = (unsigned short*)(S + 6 * MB);    // 1MB
  unsigned short* slotsb= (unsigned short*)(S + 7 * MB);    // 1MB (adjacent to updb!)
  float* gi             = (float*)(S + 8 * MB);             // 6MB
  float* gh             = (float*)(S + 14 * MB);            // 6MB (adjacent to gi!)
  float* Cpart          = (float*)(S + 20 * MB);            // 8MB
  float* rs_part        = (float*)(S + 28 * MB);            // 256KB
  float* rowinv         = (float*)(S + 29 * MB);            // 2KB
  unsigned short* wq_b  = (unsigned short*)(S + 30 * MB);   // 2MB
  unsigned short* wi_b  = (unsigned short*)(S + 32 * MB);   // 6MB
  unsigned short* wh_b  = (unsigned short*)(S + 38 * MB);   // 6MB (adjacent to wi_b!)
  unsigned short* wk_b  = (unsigned short*)(ws + 192 * MB); // 2MB  } combined W [2048][1024]
  unsigned short* wv_b  = (unsigned short*)(ws + 194 * MB); // 2MB  }
  float* slots          = (float*)(ws + 196 * MB);          // 2MB

  auto cvt = [&](const float* in, unsigned short* out, long n) {
    long n8 = n / 8;
    cvt_bf16_k<<<dim3((unsigned)((n8 + 255) / 256)), 256, 0, stream>>>(in, out, n8);
  };

  // ---- prologue ----
  cvt(Wk, wk_b, 1024L * 1024);
  cvt(Wv, wv_b, 1024L * 1024);
  rmsnorm_k<<<32768, 256, 0, stream>>>(P, inw, Pn);
  // combined K+V projection: M=32768, N=2048, K=1024 (8-phase 256^2)
  proj_k<<<1024, 512, 0, stream>>>(Pn, wk_b, kproj, vt);
  cvt(Wq, wq_b, 1024L * 1024);
  cvt(wi, wi_b, 3072L * 1024);
  cvt(wh, wh_b, 3072L * 1024);
  hipMemcpyAsync(slots, slots_in, 512L * 1024 * 4, hipMemcpyDeviceToDevice, stream);
  cvt(slots_in, slotsb, 512L * 1024);

  // ---- 3 iterations ----
  for (int it = 0; it < 3; ++it) {
    rmsnorm_k<<<512, 256, 0, stream>>>(slots, snw, sn);
    // q = sn @ Wq^T : M=512, N=1024, K=1024
    gemm_bt<64, 64, 2, 2, unsigned short, 0, 1>
        <<<dim3(16, 8, 1), 256, 0, stream>>>(sn, wq_b, qb, 1024, 1024, 1024, 1024,
                                             0, 0, 0, nullptr, nullptr, 1.f, nullptr);
    // attn[b][k][m] = softmax_k((q_b @ kproj_b^T)/32) + row partials
    gemm_bt<64, 128, 1, 4, unsigned short, 2, 1>
        <<<dim3(32, 1, 8), 256, 0, stream>>>(qb, kproj, attnb, 4096, 1024, 1024, 1024,
                                             64L * 1024, 4096L * 1024, 64L * 4096,
                                             nullptr, nullptr, 0.03125f, rs_part);
    rowinv_k<<<2, 256, 0, stream>>>(rs_part, rowinv, 32 * 4);
    // updates partials: attn_b @ vt_b^T, K=4096 split 4x1024
    gemm_bt<64, 64, 2, 2, float, 0, 4>
        <<<dim3(16, 1, 32), 256, 0, stream>>>(attnb, vt, Cpart, 1024, 1024, 4096, 4096,
                                              64L * 4096, 1024L * 4096, 64L * 1024,
                                              nullptr, nullptr, 1.f, nullptr);
    upd_reduce_k<<<512, 256, 0, stream>>>(Cpart, rowinv, updb);
    // merged gi/gh: z=0 -> gi = updb@wi^T+bi, z=1 -> gh = slotsb@wh^T+bh
    gemm_bt<64, 64, 2, 2, float, 0, 1>
        <<<dim3(48, 8, 2), 256, 0, stream>>>(updb, wi_b, gi, 3072, 1024, 1024, 1024,
                                             524288, 3145728, 1572864, bi, bh, 1.f, nullptr);
    float* dst = (it == 2) ? (float*)d_out : slots;
    gru_k<<<512, 256, 0, stream>>>(gi, gh, slots, dst, slotsb);
  }
}

// Round 4
// 438.898 us; speedup vs baseline: 2.1015x; 1.1185x over previous
//
#include <hip/hip_runtime.h>

typedef __attribute__((ext_vector_type(4))) float f32x4;
typedef __attribute__((ext_vector_type(8))) short s16x8;

static __device__ __forceinline__ unsigned short f2bf(float f) {
  unsigned int u = __builtin_bit_cast(unsigned int, f);
  u += 0x7fffu + ((u >> 16) & 1u);
  return (unsigned short)(u >> 16);
}
static __device__ __forceinline__ float sigm(float x) { return 1.0f / (1.0f + __expf(-x)); }

// async global->LDS, 16B per lane. LDS dest = wave-uniform base + lane*16.
static __device__ __forceinline__ void gload16(const unsigned short* g, unsigned short* l) {
  __builtin_amdgcn_global_load_lds(
      (const __attribute__((address_space(1))) void*)g,
      (__attribute__((address_space(3))) void*)l, 16, 0, 0);
}

#define FENCE() asm volatile("" ::: "memory")
#define BAR()   { FENCE(); __builtin_amdgcn_s_barrier(); FENCE(); }
#define LGKM0() asm volatile("s_waitcnt lgkmcnt(0)" ::: "memory")

// ================= 8-phase 256^2 projection kernel =================
// C_full[32768][2048] = A[32768][1024] @ W[2048][1024]^T, epilogue splits:
//   n<1024  -> kproj[b][m][n]          (b = gm>>12, m = gm&4095)
//   n>=1024 -> vt[b][n-1024][m]        (transposed, ushort4 along m)
__global__ __launch_bounds__(512, 2) void proj_k(
    const unsigned short* __restrict__ A, const unsigned short* __restrict__ W,
    unsigned short* __restrict__ kproj, unsigned short* __restrict__ vt) {
  __shared__ unsigned short lds[2][2][2][8192];  // [buf][A/B][half][128*64]
  const int tid = threadIdx.x, lane = tid & 63, wid = tid >> 6;
  const int wm = wid >> 2, wn = wid & 3;
  // bijective XCD swizzle (nwg = 1024 = 8*128)
  const int wg = ((int)blockIdx.x & 7) * 128 + ((int)blockIdx.x >> 3);
  const int mt = wg >> 3, nt = wg & 7;
  const unsigned short* Ap = A + (long)mt * 256 * 1024;
  const unsigned short* Wp = W + (long)nt * 256 * 1024;
  // staging source (pre-swizzled so linear LDS + swizzled read = correct)
  const int srow = lane >> 3;                       // 0..7
  const int scol = (((lane & 7) ^ srow) << 3);      // swizzled short col
  const int fr = lane & 15, fq = lane >> 4;
  const int xorv = (fr & 7) << 3;                   // read-side XOR (shorts)

#define STAGE(buf, T, h, t)                                                    \
  { const unsigned short* gp_ = (T) ? Wp : Ap;                                 \
    _Pragma("unroll") for (int p = 0; p < 2; p++) {                            \
      int r_ = wid * 16 + p * 8 + srow;                                        \
      gload16(gp_ + (long)((h) * 128 + r_) * 1024 + (long)(t) * 64 + scol,     \
              &lds[buf][T][h][(wid * 2 + p) * 512]);                           \
    } }

#define LDA_FRAG(aq)                                                           \
  { _Pragma("unroll") for (int i = 0; i < 4; i++)                              \
      _Pragma("unroll") for (int kk = 0; kk < 2; kk++)                         \
        af[i * 2 + kk] = *(const s16x8*)(Ab + ((aq) * 64 + i * 16 + fr) * 64 + \
                                         ((kk * 32 + fq * 8) ^ xorv)); }

#define LDB_FRAG(bq, arr)                                                      \
  { _Pragma("unroll") for (int j = 0; j < 2; j++)                              \
      _Pragma("unroll") for (int kk = 0; kk < 2; kk++)                         \
        arr[j * 2 + kk] = *(const s16x8*)(Bb + ((wn & 1) * 64 + ((bq) * 2 + j) * 16 + fr) * 64 + \
                                          ((kk * 32 + fq * 8) ^ xorv)); }

#define MM_Q(aq, bq, arr)                                                      \
  { __builtin_amdgcn_s_setprio(1);                                             \
    _Pragma("unroll") for (int i = 0; i < 4; i++)                              \
      _Pragma("unroll") for (int j = 0; j < 2; j++)                            \
        _Pragma("unroll") for (int kk = 0; kk < 2; kk++)                       \
          acc[(aq) * 4 + i][(bq) * 2 + j] = __builtin_amdgcn_mfma_f32_16x16x32_bf16( \
              af[i * 2 + kk], arr[j * 2 + kk], acc[(aq) * 4 + i][(bq) * 2 + j], 0, 0, 0); \
    __builtin_amdgcn_s_setprio(0); }

  f32x4 acc[8][4];
  #pragma unroll
  for (int i = 0; i < 8; i++)
    #pragma unroll
    for (int j = 0; j < 4; j++) acc[i][j] = (f32x4){0.f, 0.f, 0.f, 0.f};

  // prologue: tile0 A0,A1,B0,B1 + tile1 B0,B1 (A(1) staged during tile0)
  STAGE(0, 0, 0, 0); STAGE(0, 0, 1, 0); STAGE(0, 1, 0, 0); STAGE(0, 1, 1, 0);
  STAGE(1, 1, 0, 1); STAGE(1, 1, 1, 1);
  asm volatile("s_waitcnt vmcnt(4)" ::: "memory");
  BAR();

  s16x8 af[8], b0f[4], b1f[4];
  for (int t = 0; t < 16; ++t) {
    const int pt = t & 1;
    const unsigned short* Ab = &lds[pt][0][wm][0];
    const unsigned short* Bb = &lds[pt][1][wn >> 1][0];
    // ---- phase 1: quadrant (0,0); stage A0(t+1) ----
    LDA_FRAG(0); LDB_FRAG(0, b0f);
    if (t < 15) STAGE(pt ^ 1, 0, 0, t + 1);
    BAR(); LGKM0();
    MM_Q(0, 0, b0f);
    BAR();
    // ---- phase 2: quadrant (0,1); stage A1(t+1) ----
    LDB_FRAG(1, b1f);
    if (t < 15) STAGE(pt ^ 1, 0, 1, t + 1);
    BAR(); LGKM0();
    MM_Q(0, 1, b1f);
    BAR();
    // ---- phase 3: quadrant (1,0); stage B0(t+2) ----
    LDA_FRAG(1);
    if (t < 14) STAGE(pt, 1, 0, t + 2);
    BAR(); LGKM0();
    MM_Q(1, 0, b0f);
    BAR();
    // ---- phase 4: quadrant (1,1); stage B1(t+2); counted vmcnt ----
    if (t < 14) STAGE(pt, 1, 1, t + 2);
    if (t == 14) { asm volatile("s_waitcnt vmcnt(0)" ::: "memory"); }
    else         { asm volatile("s_waitcnt vmcnt(4)" ::: "memory"); }
    BAR();
    MM_Q(1, 1, b1f);
    BAR();
  }

  // ---- epilogue: split K/V store ----
  const int nbase = nt * 256 + wn * 64;
  const bool kside = (nbase < 1024);
  #pragma unroll
  for (int i = 0; i < 8; i++) {
    const int gm0 = mt * 256 + wm * 128 + i * 16 + fq * 4;
    const int b = gm0 >> 12, mrow = gm0 & 4095;
    #pragma unroll
    for (int j = 0; j < 4; j++) {
      const int n = nbase + j * 16 + fr;
      if (kside) {
        unsigned short* dst = kproj + ((long)b * 4096 + mrow) * 1024 + n;
        #pragma unroll
        for (int q = 0; q < 4; q++) dst[(long)q * 1024] = f2bf(acc[i][j][q]);
      } else {
        ushort4 o;
        o.x = f2bf(acc[i][j][0]); o.y = f2bf(acc[i][j][1]);
        o.z = f2bf(acc[i][j][2]); o.w = f2bf(acc[i][j][3]);
        *(ushort4*)(vt + ((long)b * 1024 + (n - 1024)) * 4096 + mrow) = o;
      }
    }
  }
#undef STAGE
#undef LDA_FRAG
#undef LDB_FRAG
#undef MM_Q
}

// ---------------- rmsnorm rows of length 1024: fp32 -> bf16 ----------------
__global__ __launch_bounds__(256) void rmsnorm_k(const float* __restrict__ x,
                                                 const float* __restrict__ w,
                                                 unsigned short* __restrict__ y) {
  const int row = blockIdx.x;
  const int tid = threadIdx.x;
  const float4* xp = (const float4*)(x + (long)row * 1024);
  float4 v = xp[tid];
  float ss = v.x * v.x + v.y * v.y + v.z * v.z + v.w * v.w;
  #pragma unroll
  for (int off = 32; off; off >>= 1) ss += __shfl_xor(ss, off, 64);
  __shared__ float sb[4];
  if ((tid & 63) == 0) sb[tid >> 6] = ss;
  __syncthreads();
  float tot = sb[0] + sb[1] + sb[2] + sb[3];
  float rs = rsqrtf(tot * (1.0f / 1024.0f) + 1e-6f);
  const float4* wp = (const float4*)w;
  float4 wv = wp[tid];
  ushort4 o;
  o.x = f2bf(v.x * rs * wv.x);
  o.y = f2bf(v.y * rs * wv.y);
  o.z = f2bf(v.z * rs * wv.z);
  o.w = f2bf(v.w * rs * wv.w);
  ((ushort4*)y)[(long)row * 256 + tid] = o;
}

// ---------------- fp32 -> bf16 convert (8 elems/thread) ----------------
__global__ __launch_bounds__(256) void cvt_bf16_k(const float* __restrict__ in,
                                                  unsigned short* __restrict__ out,
                                                  long n8) {
  long i = (long)blockIdx.x * 256 + threadIdx.x;
  if (i >= n8) return;
  const float4* p = (const float4*)in;
  float4 a = p[i * 2], b = p[i * 2 + 1];
  ushort4 lo, hi;
  lo.x = f2bf(a.x); lo.y = f2bf(a.y); lo.z = f2bf(a.z); lo.w = f2bf(a.w);
  hi.x = f2bf(b.x); hi.y = f2bf(b.y); hi.z = f2bf(b.z); hi.w = f2bf(b.w);
  ushort4* o = (ushort4*)out;
  o[i * 2] = lo;
  o[i * 2 + 1] = hi;
}

// ---------------- GEMM: C = alpha * A[M][K] @ W[N][K]^T (+bias) ----------------
// EPI: 0 = plain store; 2 = softmax over M(=64) -> bf16 attn + row partials.
// SPLIT: K-split batching. bias2: used for odd blockIdx.z (merged gi/gh).
template <int BM, int BN, int WR, int WC, typename CT, int EPI, int SPLIT>
__global__ __launch_bounds__(WR * WC * 64) void gemm_bt(
    const unsigned short* __restrict__ A, const unsigned short* __restrict__ W,
    CT* __restrict__ C, int N, int Klen, int lda, int ldw,
    long sA, long sW, long sC, const float* __restrict__ bias,
    const float* __restrict__ bias2, float alpha, float* __restrict__ rs_part) {
  constexpr int BK = 64;
  constexpr int NT = WR * WC * 64;
  static_assert(NT == 256, "256 threads");
  constexpr int WSM = BM / WR, WSN = BN / WC;
  constexpr int MR = WSM / 16, NR = WSN / 16;
  constexpr int SEG_A = BM / 8, SEG_W = BN / 8;
  constexpr int PA = SEG_A / 4, PW = SEG_W / 4;
  static_assert(SEG_A % 4 == 0 && SEG_W % 4 == 0, "seg divisibility");
  __shared__ unsigned short As[BM * BK];
  __shared__ unsigned short Ws[BN * BK];
  const int tid = threadIdx.x, lane = tid & 63, wid = tid >> 6;
  const int wr = wid / WC, wc = wid % WC;
  const int tileN = blockIdx.x * BN, tileM = blockIdx.y * BM;
  const int zb = blockIdx.z / SPLIT, zs = blockIdx.z % SPLIT;
  A += (long)zb * sA + (long)zs * Klen;
  W += (long)zb * sW + (long)zs * Klen;
  C += (long)blockIdx.z * sC;
  const float* bp = (bias2 && (blockIdx.z & 1)) ? bias2 : bias;
  const int srow = lane >> 3;
  const int scol = (lane & 7) * 8;
  f32x4 acc[MR][NR];
  #pragma unroll
  for (int i = 0; i < MR; i++)
    #pragma unroll
    for (int j = 0; j < NR; j++) acc[i][j] = (f32x4){0.f, 0.f, 0.f, 0.f};
  const int fr = lane & 15, fq = lane >> 4;

  for (int k0 = 0; k0 < Klen; k0 += BK) {
    #pragma unroll
    for (int p = 0; p < PA; p++) {
      int seg = wid * PA + p;
      gload16(A + (long)(tileM + seg * 8 + srow) * lda + k0 + scol, &As[seg * 512]);
    }
    #pragma unroll
    for (int p = 0; p < PW; p++) {
      int seg = wid * PW + p;
      gload16(W + (long)(tileN + seg * 8 + srow) * ldw + k0 + scol, &Ws[seg * 512]);
    }
    __syncthreads();
    #pragma unroll
    for (int kk = 0; kk < BK; kk += 32) {
      s16x8 af[MR], bf[NR];
      #pragma unroll
      for (int i = 0; i < MR; i++)
        af[i] = *(const s16x8*)(&As[(wr * WSM + i * 16 + fr) * BK + kk + fq * 8]);
      #pragma unroll
      for (int j = 0; j < NR; j++)
        bf[j] = *(const s16x8*)(&Ws[(wc * WSN + j * 16 + fr) * BK + kk + fq * 8]);
      #pragma unroll
      for (int i = 0; i < MR; i++)
        #pragma unroll
        for (int j = 0; j < NR; j++)
          acc[i][j] = __builtin_amdgcn_mfma_f32_16x16x32_bf16(af[i], bf[j], acc[i][j], 0, 0, 0);
    }
    __syncthreads();
  }

  if constexpr (EPI == 2) {
    static_assert(WR == 1 && BM == 64, "softmax epilogue needs full-M wave");
    #pragma unroll
    for (int i = 0; i < MR; i++)
      #pragma unroll
      for (int j = 0; j < NR; j++)
        #pragma unroll
        for (int q = 0; q < 4; q++) acc[i][j][q] *= alpha;
    float inv[NR];
    #pragma unroll
    for (int j = 0; j < NR; j++) {
      float mx = -1e30f;
      #pragma unroll
      for (int i = 0; i < MR; i++)
        #pragma unroll
        for (int q = 0; q < 4; q++) mx = fmaxf(mx, acc[i][j][q]);
      mx = fmaxf(mx, __shfl_xor(mx, 16, 64));
      mx = fmaxf(mx, __shfl_xor(mx, 32, 64));
      float sm = 0.f;
      #pragma unroll
      for (int i = 0; i < MR; i++)
        #pragma unroll
        for (int q = 0; q < 4; q++) {
          float e = __expf(acc[i][j][q] - mx);
          acc[i][j][q] = e;
          sm += e;
        }
      sm += __shfl_xor(sm, 16, 64);
      sm += __shfl_xor(sm, 32, 64);
      inv[j] = 1.f / sm;
    }
    float rp[MR][4];
    #pragma unroll
    for (int i = 0; i < MR; i++)
      #pragma unroll
      for (int q = 0; q < 4; q++) rp[i][q] = 0.f;
    unsigned short* Cs = (unsigned short*)C;
    #pragma unroll
    for (int i = 0; i < MR; i++)
      #pragma unroll
      for (int j = 0; j < NR; j++)
        #pragma unroll
        for (int q = 0; q < 4; q++) {
          float a = acc[i][j][q] * inv[j];
          rp[i][q] += a;
          Cs[(long)(i * 16 + fq * 4 + q) * N + tileN + wc * WSN + j * 16 + fr] = f2bf(a);
        }
    #pragma unroll
    for (int off = 1; off <= 8; off <<= 1)
      #pragma unroll
      for (int i = 0; i < MR; i++)
        #pragma unroll
        for (int q = 0; q < 4; q++) rp[i][q] += __shfl_xor(rp[i][q], off, 64);
    if (fr == 0) {
      const int rld = gridDim.x * WC;
      #pragma unroll
      for (int i = 0; i < MR; i++)
        #pragma unroll
        for (int q = 0; q < 4; q++)
          rs_part[((long)zb * 64 + i * 16 + fq * 4 + q) * rld + blockIdx.x * WC + wc] = rp[i][q];
    }
    return;
  }

  #pragma unroll
  for (int i = 0; i < MR; i++) {
    const int mbase = tileM + wr * WSM + i * 16 + fq * 4;
    #pragma unroll
    for (int j = 0; j < NR; j++) {
      const int n = tileN + wc * WSN + j * 16 + fr;
      const float bv = bp ? bp[n] : 0.f;
      #pragma unroll
      for (int q = 0; q < 4; q++) {
        float v = acc[i][j][q] * alpha + bv;
        if constexpr (sizeof(CT) == 2)
          C[(long)(mbase + q) * N + n] = f2bf(v);
        else
          C[(long)(mbase + q) * N + n] = v;
      }
    }
  }
}

// ---- reduce 4 K-splits; in-block rowsum of rs_part -> rowinv; scale; cast bf16 ----
// block = one (b,k) row (512 blocks x 256 threads, 4 elems/thread)
__global__ __launch_bounds__(256) void upd_reduce_k(const float* __restrict__ part,
                                                    const float* __restrict__ rs_part,
                                                    unsigned short* __restrict__ out) {
  const int row = blockIdx.x;  // b*64 + k
  const int tid = threadIdx.x;
  float s = (tid < 128) ? rs_part[(long)row * 128 + tid] : 0.f;
  #pragma unroll
  for (int off = 32; off; off >>= 1) s += __shfl_xor(s, off, 64);
  __shared__ float sb[4];
  if ((tid & 63) == 0) sb[tid >> 6] = s;
  __syncthreads();
  const float inv = 1.f / (sb[0] + sb[1] + sb[2] + sb[3] + 1e-6f);
  const float* base = part + (long)(row >> 6) * 4 * 65536 + (long)(row & 63) * 1024 + tid * 4;
  float4 acc4 = {0.f, 0.f, 0.f, 0.f};
  #pragma unroll
  for (int sp = 0; sp < 4; sp++) {
    float4 v = *(const float4*)(base + (long)sp * 65536);
    acc4.x += v.x; acc4.y += v.y; acc4.z += v.z; acc4.w += v.w;
  }
  ushort4 o;
  o.x = f2bf(acc4.x * inv); o.y = f2bf(acc4.y * inv);
  o.z = f2bf(acc4.z * inv); o.w = f2bf(acc4.w * inv);
  ((ushort4*)out)[(long)row * 256 + tid] = o;
}

// ---- GRU combine + fused rmsnorm of the new slots (block = one row) ----
// writes: out (fp32 new slots), out_bf (bf16 new slots), sn_out (bf16 rmsnorm'd)
__global__ __launch_bounds__(256) void gru_k(const float* __restrict__ gi,
                                             const float* __restrict__ gh,
                                             const float* __restrict__ h,
                                             const float* __restrict__ snw,
                                             float* __restrict__ out,
                                             unsigned short* __restrict__ out_bf,
                                             unsigned short* __restrict__ sn_out) {
  const int r = blockIdx.x;
  const int tid = threadIdx.x;
  const int c = tid * 4;
  const long gb = (long)r * 3072 + c;
  float4 ir = *(const float4*)(gi + gb);
  float4 iz = *(const float4*)(gi + gb + 1024);
  float4 in = *(const float4*)(gi + gb + 2048);
  float4 hr = *(const float4*)(gh + gb);
  float4 hz = *(const float4*)(gh + gb + 1024);
  float4 hn = *(const float4*)(gh + gb + 2048);
  float4 hv = *(const float4*)(h + (long)r * 1024 + c);
  float4 o;
  { float rr = sigm(ir.x + hr.x), zz = sigm(iz.x + hz.x);
    float nn = tanhf(in.x + rr * hn.x); o.x = (1.f - zz) * nn + zz * hv.x; }
  { float rr = sigm(ir.y + hr.y), zz = sigm(iz.y + hz.y);
    float nn = tanhf(in.y + rr * hn.y); o.y = (1.f - zz) * nn + zz * hv.y; }
  { float rr = sigm(ir.z + hr.z), zz = sigm(iz.z + hz.z);
    float nn = tanhf(in.z + rr * hn.z); o.z = (1.f - zz) * nn + zz * hv.z; }
  { float rr = sigm(ir.w + hr.w), zz = sigm(iz.w + hz.w);
    float nn = tanhf(in.w + rr * hn.w); o.w = (1.f - zz) * nn + zz * hv.w; }
  *(float4*)(out + (long)r * 1024 + c) = o;
  ushort4 ob;
  ob.x = f2bf(o.x); ob.y = f2bf(o.y); ob.z = f2bf(o.z); ob.w = f2bf(o.w);
  *(ushort4*)(out_bf + (long)r * 1024 + c) = ob;
  // fused rmsnorm of the new row
  float ss = o.x * o.x + o.y * o.y + o.z * o.z + o.w * o.w;
  #pragma unroll
  for (int off = 32; off; off >>= 1) ss += __shfl_xor(ss, off, 64);
  __shared__ float sb[4];
  if ((tid & 63) == 0) sb[tid >> 6] = ss;
  __syncthreads();
  const float tot = sb[0] + sb[1] + sb[2] + sb[3];
  const float rs = rsqrtf(tot * (1.0f / 1024.0f) + 1e-6f);
  float4 wv = *(const float4*)(snw + c);
  ushort4 so;
  so.x = f2bf(o.x * rs * wv.x); so.y = f2bf(o.y * rs * wv.y);
  so.z = f2bf(o.z * rs * wv.z); so.w = f2bf(o.w * rs * wv.w);
  *(ushort4*)(sn_out + (long)r * 1024 + c) = so;
}

extern "C" void kernel_launch(void* const* d_in, const int* in_sizes, int n_in,
                              void* d_out, int out_size, void* d_ws, size_t ws_size,
                              hipStream_t stream) {
  const float* slots_in = (const float*)d_in[0];
  const float* P        = (const float*)d_in[1];
  const float* Wq       = (const float*)d_in[2];
  const float* Wk       = (const float*)d_in[3];
  const float* Wv       = (const float*)d_in[4];
  const float* wi       = (const float*)d_in[5];
  const float* wh       = (const float*)d_in[6];
  const float* bi       = (const float*)d_in[7];
  const float* bh       = (const float*)d_in[8];
  const float* snw      = (const float*)d_in[9];
  const float* inw      = (const float*)d_in[10];

  const size_t MB = 1024ull * 1024ull;
  char* ws = (char*)d_ws;
  unsigned short* kproj = (unsigned short*)(ws, ws + 0);    // 64MB [b][m][e] bf16
  unsigned short* vt    = (unsigned short*)(ws + 64 * MB);  // 64MB [b][e][m] bf16
  char* S               = ws + 128 * MB;                    // 64MB reuse region
  unsigned short* Pn    = (unsigned short*)(S);             // prologue only (64MB)
  unsigned short* sn    = (unsigned short*)(S);             // 1MB
  unsigned short* qb    = (unsigned short*)(S + 1 * MB);    // 1MB
  unsigned short* attnb = (unsigned short*)(S + 2 * MB);    // 4MB
  unsigned short* updb  = (unsigned short*)(S + 6 * MB);    // 1MB
  unsigned short* slotsb= (unsigned short*)(S + 7 * MB);    // 1MB (adjacent to updb!)
  float* gi             = (float*)(S + 8 * MB);             // 6MB
  float* gh             = (float*)(S + 14 * MB);            // 6MB (adjacent to gi!)
  float* Cpart          = (float*)(S + 20 * MB);            // 8MB
  float* rs_part        = (float*)(S + 28 * MB);            // 256KB
  unsigned short* wq_b  = (unsigned short*)(S + 30 * MB);   // 2MB
  unsigned short* wi_b  = (unsigned short*)(S + 32 * MB);   // 6MB
  unsigned short* wh_b  = (unsigned short*)(S + 38 * MB);   // 6MB (adjacent to wi_b!)
  unsigned short* wk_b  = (unsigned short*)(ws + 192 * MB); // 2MB  } combined W [2048][1024]
  unsigned short* wv_b  = (unsigned short*)(ws + 194 * MB); // 2MB  }
  float* slots          = (float*)(ws + 196 * MB);          // 2MB

  auto cvt = [&](const float* in, unsigned short* out, long n) {
    long n8 = n / 8;
    cvt_bf16_k<<<dim3((unsigned)((n8 + 255) / 256)), 256, 0, stream>>>(in, out, n8);
  };

  // ---- prologue ----
  cvt(Wk, wk_b, 1024L * 1024);
  cvt(Wv, wv_b, 1024L * 1024);
  rmsnorm_k<<<32768, 256, 0, stream>>>(P, inw, Pn);
  // combined K+V projection: M=32768, N=2048, K=1024 (8-phase 256^2)
  proj_k<<<1024, 512, 0, stream>>>(Pn, wk_b, kproj, vt);
  cvt(Wq, wq_b, 1024L * 1024);
  cvt(wi, wi_b, 3072L * 1024);
  cvt(wh, wh_b, 3072L * 1024);
  cvt(slots_in, slotsb, 512L * 1024);
  rmsnorm_k<<<512, 256, 0, stream>>>(slots_in, snw, sn);

  // ---- 3 iterations (6 dispatches each) ----
  for (int it = 0; it < 3; ++it) {
    // q = sn @ Wq^T : M=512, N=1024, K=1024
    gemm_bt<64, 64, 2, 2, unsigned short, 0, 1>
        <<<dim3(16, 8, 1), 256, 0, stream>>>(sn, wq_b, qb, 1024, 1024, 1024, 1024,
                                             0, 0, 0, nullptr, nullptr, 1.f, nullptr);
    // attn[b][k][m] = softmax_k((q_b @ kproj_b^T)/32) + row partials
    gemm_bt<64, 128, 1, 4, unsigned short, 2, 1>
        <<<dim3(32, 1, 8), 256, 0, stream>>>(qb, kproj, attnb, 4096, 1024, 1024, 1024,
                                             64L * 1024, 4096L * 1024, 64L * 4096,
                                             nullptr, nullptr, 0.03125f, rs_part);
    // updates partials: attn_b @ vt_b^T, K=4096 split 4x1024
    gemm_bt<64, 64, 2, 2, float, 0, 4>
        <<<dim3(16, 1, 32), 256, 0, stream>>>(attnb, vt, Cpart, 1024, 1024, 4096, 4096,
                                              64L * 4096, 1024L * 4096, 64L * 1024,
                                              nullptr, nullptr, 1.f, nullptr);
    upd_reduce_k<<<512, 256, 0, stream>>>(Cpart, rs_part, updb);
    // merged gi/gh: z=0 -> gi = updb@wi^T+bi, z=1 -> gh = slotsb@wh^T+bh
    gemm_bt<64, 64, 2, 2, float, 0, 1>
        <<<dim3(48, 8, 2), 256, 0, stream>>>(updb, wi_b, gi, 3072, 1024, 1024, 1024,
                                             524288, 3145728, 1572864, bi, bh, 1.f, nullptr);
    const float* hsrc = (it == 0) ? slots_in : slots;
    float* dst = (it == 2) ? (float*)d_out : slots;
    gru_k<<<512, 256, 0, stream>>>(gi, gh, hsrc, snw, dst, slotsb, sn);
  }
}